// Round 3
// baseline (389.814 us; speedup 1.0000x reference)
//
#include <hip/hip_runtime.h>

typedef _Float16 half8 __attribute__((ext_vector_type(8)));
typedef float floatx4 __attribute__((ext_vector_type(4)));

constexpr int Bn = 16, Cn = 256, Hn = 64, Wn = 96;
constexpr int HW = Hn * Wn;          // 6144
constexpr int Dn = 21, ND = Dn * Dn; // 441
// padded f2 spatial dims (pad=20 each side)
constexpr int PH = Hn + 40;          // 104
constexpr int PW = Wn + 40;          // 136
constexpr int PHW = PH * PW;         // 14144
// pass-2 tile
constexpr int TY = 8, TX = 16;
constexpr int NTY = Hn / TY;         // 8
constexpr int NTX = Wn / TX;         // 6
constexpr int NJ = (TX + 40) / 2;    // 28 class-window cols
constexpr int Mrows = 32;            // p1 pixels per class (4x8 grid)
// split-G: window rows (24 total) in two chunks so LDS fits 4 wg/CU
constexpr int GROWS = 14;            // max rows per chunk
constexpr int GPITCH = 396;          // f16 pitch: 4-row delta = 792B = bank+24 -> disjoint octets
// LDS = 32*396*2 = 25344 B -> 4 wg/CU (VGPR band 65..128 caps at 16 waves/CU)

constexpr size_t F1T_BYTES = (size_t)Bn * HW * Cn * 2;   // 50,331,648
constexpr size_t F2T_BYTES = (size_t)Bn * PHW * Cn * 2;  // 115,867,648
constexpr size_t WS_NEEDED = F1T_BYTES + F2T_BYTES;

// ---------------- pass 1a: f1 [B,C,H,W] f32 -> [B,HW,C] f16 (LDS-free) ----
__global__ __launch_bounds__(256)
void tconv_f1(const float* __restrict__ in, _Float16* __restrict__ outp) {
  const int blk = blockIdx.x;
  const int b = blk / (HW / 64);
  const int px0 = (blk % (HW / 64)) * 64;
  const int t = threadIdx.x;
  const int pxl = t >> 2;            // 0..63
  const int g = t & 3;
  const int px = px0 + pxl;
  const float* src = in + (size_t)b * Cn * HW + px;
  _Float16* dst = outp + ((size_t)b * HW + px) * Cn;
#pragma unroll
  for (int it = 0; it < 8; ++it) {
    const int c0 = (g + it * 4) * 8;
    half8 v;
#pragma unroll
    for (int k = 0; k < 8; ++k)
      v[k] = (_Float16)src[(size_t)(c0 + k) * HW];
    *(half8*)(dst + c0) = v;         // 16B store, lanes g=0..3 contiguous 64B
  }
}

// ---------------- pass 1b: f2 -> zero-padded [B,PH*PW,C] f16 --------------
__global__ __launch_bounds__(256)
void tconv_f2pad(const float* __restrict__ in, _Float16* __restrict__ outp) {
  const int blk = blockIdx.x;
  const int b = blk / (PHW / 64);
  const int ppx0 = (blk % (PHW / 64)) * 64;
  const int t = threadIdx.x;
  const int pxl = t >> 2;
  const int g = t & 3;
  const int ppx = ppx0 + pxl;
  const int y = ppx / PW;
  const int x = ppx - y * PW;
  const int yy = y - 20, xx = x - 20;
  const bool valid = (yy >= 0) & (yy < Hn) & (xx >= 0) & (xx < Wn);
  const float* src = in + (size_t)b * Cn * HW + (valid ? (yy * Wn + xx) : 0);
  _Float16* dst = outp + ((size_t)b * PHW + ppx) * Cn;
#pragma unroll
  for (int it = 0; it < 8; ++it) {
    const int c0 = (g + it * 4) * 8;
    half8 v;
#pragma unroll
    for (int k = 0; k < 8; ++k) {
      const float f = src[(size_t)(c0 + k) * HW];
      v[k] = (_Float16)(valid ? f : 0.0f);
    }
    *(half8*)(dst + c0) = v;
  }
}

// ---------------- pass 2: correlation via MFMA ----------------------------
// One wg = one 8x16 tile, 4 parity classes x 2 window-row chunks sequentially.
// Per (class,chunk): G[m=32][n<=392] = f1_tile . f2_window rows [i0,i0+nrows)
// via mfma_f32_16x16x32_f16; G (f16, pre-scaled 1/C) in LDS -> gather epilogue
// for dy in the chunk's range.
__global__ __launch_bounds__(256, 4)
void corr2(const _Float16* __restrict__ f1t, const _Float16* __restrict__ f2t,
           float* __restrict__ out) {
  __shared__ _Float16 G[Mrows * GPITCH];  // 25,344 B

  // bijective XCD swizzle: 768 wgs = 8 XCDs x 96 contiguous tiles
  int bid = (int)blockIdx.x;
  bid = (bid & 7) * 96 + (bid >> 3);
  const int tx = bid % NTX;
  const int tmp = bid / NTX;
  const int ty = tmp % NTY;
  const int b = tmp / NTY;
  const int y0 = ty * TY, x0 = tx * TX;

  const int t = threadIdx.x;
  const int lane = t & 63;
  const int wave = t >> 6;
  const int l15 = lane & 15;
  const int lk = lane >> 4;

  const _Float16* f1b = f1t + (size_t)b * HW * Cn;
  const _Float16* f2b = f2t + (size_t)b * PHW * Cn;
  const float invc = 1.0f / 256.0f;

  for (int cls = 0; cls < 4; ++cls) {
    const int qa = cls >> 1, qb = cls & 1;

    // A fragments for both m-tiles, held in registers (64 VGPR)
    half8 afrag[2][8];
#pragma unroll
    for (int mt = 0; mt < 2; ++mt) {
      const int m = mt * 16 + l15;
      const int ay = y0 + qa + 2 * (m >> 3);
      const int ax = x0 + qb + 2 * (m & 7);
      const _Float16* ap = f1b + (size_t)(ay * Wn + ax) * Cn + lk * 8;
#pragma unroll
      for (int ks = 0; ks < 8; ++ks)
        afrag[mt][ks] = *(const half8*)(ap + ks * 32);
    }

#pragma unroll
    for (int chunk = 0; chunk < 2; ++chunk) {
      const int i0 = chunk ? 11 : 0;        // window row offset
      const int nrows = chunk ? 13 : 14;    // rows in this chunk
      const int NNc = nrows * NJ;           // 392 / 364
      const int ntiles = (NNc + 15) / 16;   // 25 / 23

      for (int nt = wave; nt < ntiles; nt += 4) {
        const int n = nt * 16 + l15;
        const bool nvalid = n < NNc;
        const int nc = nvalid ? n : 0;
        const int i = nc / NJ + i0;
        const int j = nc % NJ;
        const int py = y0 + qa + 2 * i;     // padded coords
        const int px = x0 + qb + 2 * j;
        const _Float16* bp = f2b + (size_t)(py * PW + px) * Cn + lk * 8;
        half8 bfrag[8];
#pragma unroll
        for (int ks = 0; ks < 8; ++ks)
          bfrag[ks] = *(const half8*)(bp + ks * 32);

        floatx4 acc0 = {0.f, 0.f, 0.f, 0.f};
        floatx4 acc1 = {0.f, 0.f, 0.f, 0.f};
#pragma unroll
        for (int ks = 0; ks < 8; ++ks) {
          acc0 = __builtin_amdgcn_mfma_f32_16x16x32_f16(afrag[0][ks], bfrag[ks], acc0, 0, 0, 0);
          acc1 = __builtin_amdgcn_mfma_f32_16x16x32_f16(afrag[1][ks], bfrag[ks], acc1, 0, 0, 0);
        }
        if (nvalid) {
#pragma unroll
          for (int r = 0; r < 4; ++r) {
            G[(4 * lk + r) * GPITCH + n]      = (_Float16)(acc0[r] * invc);
            G[(16 + 4 * lk + r) * GPITCH + n] = (_Float16)(acc1[r] * invc);
          }
        }
      }
      __syncthreads();

      // epilogue for this chunk's dy range:
      // chunk 0: dy in [0,10] (231 ch); chunk 1: dy in [11,20] (210 ch)
      {
        const int dyLo = chunk ? 11 : 0;
        const int ndch = chunk ? 210 : 231;
        const int m = t & 31;
        const int alpha = m >> 3, beta = m & 7;
        const int yy = y0 + qa + 2 * alpha;
        const int xx = x0 + qb + 2 * beta;
        float* ob = out + (size_t)b * ND * HW + yy * Wn + xx;
        const _Float16* Grow = G + m * GPITCH + (alpha - i0) * NJ + beta;
        int dl = t >> 5;                    // 0..7 (<21 so local dy starts 0)
        int dy = dyLo, dx = dl;
        while (dl < ndch) {
          const float v = (float)Grow[dy * NJ + dx];
          __builtin_nontemporal_store(v, &ob[(size_t)(dy * Dn + dx) * HW]);
          dl += 8;
          dx += 8;
          if (dx >= Dn) { dx -= Dn; dy += 1; }
        }
      }
      __syncthreads();
    }
  }
}

// ---------------- fallback (round-1 kernel) if ws too small ---------------
constexpr int FTY = 8, FTX = 8;
constexpr int FNTY = Hn / FTY, FNTX = Wn / FTX;
constexpr int FNJ = 24, FNTILES = 36, FGP = 580;

__global__ __launch_bounds__(256, 4)
void corr_fallback(const float* __restrict__ f1, const float* __restrict__ f2,
                   float* __restrict__ out) {
  __shared__ float G[16 * FGP];
  const int bid = blockIdx.x;
  const int cls = bid & 3;
  const int t2 = bid >> 2;
  const int tx = t2 % FNTX;
  const int t3 = t2 / FNTX;
  const int ty = t3 % FNTY;
  const int b = t3 / FNTY;
  const int qa = cls >> 1, qb = cls & 1;
  const int y0 = ty * FTY, x0 = tx * FTX;
  const int lane = threadIdx.x & 63;
  const int wave = threadIdx.x >> 6;
  const int l15 = lane & 15;
  const int lk = lane >> 4;
  const float* f1b = f1 + b * (Cn * HW);
  const float* f2b = f2 + b * (Cn * HW);
  const int ay = y0 + qa + 2 * (l15 >> 2);
  const int ax = x0 + qb + 2 * (l15 & 3);
  const float* f1p = f1b + ay * Wn + ax;
  half8 afrag[8];
#pragma unroll
  for (int ks = 0; ks < 8; ++ks)
#pragma unroll
    for (int tt = 0; tt < 8; ++tt)
      afrag[ks][tt] = (_Float16)f1p[(ks * 32 + lk * 8 + tt) * HW];
  const int nt0 = wave * (FNTILES / 4);
  for (int nt = nt0; nt < nt0 + FNTILES / 4; ++nt) {
    const unsigned n = nt * 16 + l15;
    const int i = n / (unsigned)FNJ;
    const int j = n % (unsigned)FNJ;
    const int y2 = y0 - 20 + qa + 2 * i;
    const int x2 = x0 - 20 + qb + 2 * j;
    const bool inb = (y2 >= 0) & (y2 < Hn) & (x2 >= 0) & (x2 < Wn);
    const float* f2p = f2b + (inb ? (y2 * Wn + x2) : 0);
    floatx4 acc = {0.f, 0.f, 0.f, 0.f};
#pragma unroll
    for (int ks = 0; ks < 8; ++ks) {
      half8 bfrag;
#pragma unroll
      for (int tt = 0; tt < 8; ++tt) {
        const float v = f2p[(ks * 32 + lk * 8 + tt) * HW];
        bfrag[tt] = (_Float16)(inb ? v : 0.0f);
      }
      acc = __builtin_amdgcn_mfma_f32_16x16x32_f16(afrag[ks], bfrag, acc, 0, 0, 0);
    }
#pragma unroll
    for (int r = 0; r < 4; ++r)
      G[(4 * lk + r) * FGP + n] = acc[r];
  }
  __syncthreads();
  float* outb = out + b * (ND * HW);
  const float invc = 1.0f / 256.0f;
  for (int o = threadIdx.x; o < ND * 16; o += 256) {
    const int d = o >> 4;
    const int m = o & 15;
    const int dy = (unsigned)d / 21u;
    const int dx = (unsigned)d % 21u;
    const int alpha = m >> 2, beta = m & 3;
    const float val = G[m * FGP + (alpha + dy) * FNJ + (beta + dx)] * invc;
    outb[d * HW + (y0 + qa + 2 * alpha) * Wn + (x0 + qb + 2 * beta)] = val;
  }
}

extern "C" void kernel_launch(void* const* d_in, const int* in_sizes, int n_in,
                              void* d_out, int out_size, void* d_ws, size_t ws_size,
                              hipStream_t stream) {
  const float* f1 = (const float*)d_in[0];
  const float* f2 = (const float*)d_in[1];
  float* out = (float*)d_out;
  if (ws_size >= WS_NEEDED) {
    _Float16* f1t = (_Float16*)d_ws;
    _Float16* f2t = (_Float16*)((char*)d_ws + F1T_BYTES);
    tconv_f1<<<dim3(Bn * (HW / 64)), dim3(256), 0, stream>>>(f1, f1t);
    tconv_f2pad<<<dim3(Bn * (PHW / 64)), dim3(256), 0, stream>>>(f2, f2t);
    corr2<<<dim3(Bn * NTY * NTX), dim3(256), 0, stream>>>(f1t, f2t, out);
  } else {
    corr_fallback<<<dim3(Bn * FNTY * FNTX * 4), dim3(256), 0, stream>>>(f1, f2, out);
  }
}

// Round 4
// 285.310 us; speedup vs baseline: 1.3663x; 1.3663x over previous
//
#include <hip/hip_runtime.h>

typedef _Float16 half8 __attribute__((ext_vector_type(8)));
typedef float floatx4 __attribute__((ext_vector_type(4)));

constexpr int Bn = 16, Cn = 256, Hn = 64, Wn = 96;
constexpr int HW = Hn * Wn;          // 6144
constexpr int Dn = 21, ND = Dn * Dn; // 441
// padded f2 spatial dims (pad=20 each side)
constexpr int PH = Hn + 40;          // 104
constexpr int PW = Wn + 40;          // 136
constexpr int PHW = PH * PW;         // 14144
// pass-2 tile
constexpr int TY = 8, TX = 16;
constexpr int NTY = Hn / TY;         // 8
constexpr int NTX = Wn / TX;         // 6
constexpr int NJ = (TX + 40) / 2;    // 28 window cols per parity
constexpr int GPITCH = 396;          // f16 pitch (4-row delta -> disjoint bank octets)
// LDS: 2 parity classes x 32 rows x 396 f16 = 50688 B -> 3 wg/CU

constexpr size_t F1T_BYTES = (size_t)Bn * HW * Cn * 2;   // 50,331,648
constexpr size_t F2T_BYTES = (size_t)Bn * PHW * Cn * 2;  // 115,867,648
constexpr size_t WS_NEEDED = F1T_BYTES + F2T_BYTES;

constexpr int F1_BLKS = Bn * (HW / 64);    // 1536
constexpr int F2_BLKS = Bn * (PHW / 64);   // 3536

// ---------------- pass 1 (merged): f32 BCHW -> f16 pixel-major ------------
__global__ __launch_bounds__(256)
void tconv_all(const float* __restrict__ f1, const float* __restrict__ f2,
               _Float16* __restrict__ f1t, _Float16* __restrict__ f2t) {
  int blk = blockIdx.x;
  const int t = threadIdx.x;
  const int pxl = t >> 2;            // 0..63
  const int g = t & 3;
  if (blk < F1_BLKS) {
    const int b = blk / (HW / 64);
    const int px = (blk % (HW / 64)) * 64 + pxl;
    const float* src = f1 + (size_t)b * Cn * HW + px;
    _Float16* dst = f1t + ((size_t)b * HW + px) * Cn;
#pragma unroll
    for (int it = 0; it < 8; ++it) {
      const int c0 = (g + it * 4) * 8;
      half8 v;
#pragma unroll
      for (int k = 0; k < 8; ++k)
        v[k] = (_Float16)src[(size_t)(c0 + k) * HW];
      *(half8*)(dst + c0) = v;
    }
  } else {
    blk -= F1_BLKS;
    const int b = blk / (PHW / 64);
    const int ppx = (blk % (PHW / 64)) * 64 + pxl;
    const int y = ppx / PW;
    const int x = ppx - y * PW;
    const int yy = y - 20, xx = x - 20;
    const bool valid = (yy >= 0) & (yy < Hn) & (xx >= 0) & (xx < Wn);
    const float* src = f2 + (size_t)b * Cn * HW + (valid ? (yy * Wn + xx) : 0);
    _Float16* dst = f2t + ((size_t)b * PHW + ppx) * Cn;
#pragma unroll
    for (int it = 0; it < 8; ++it) {
      const int c0 = (g + it * 4) * 8;
      half8 v;
#pragma unroll
      for (int k = 0; k < 8; ++k) {
        const float f = src[(size_t)(c0 + k) * HW];
        v[k] = (_Float16)(valid ? f : 0.0f);
      }
      *(half8*)(dst + c0) = v;
    }
  }
}

// ---------------- pass 2: correlation via MFMA ----------------------------
// One wg = (b, qa, 8x16 tile, window-row chunk), BOTH x-parity classes.
// Per qb: G[qb][m=32][n<=392] = f1_tile . f2_window rows [i0,i0+nrows)
// via mfma_f32_16x16x32_f16 (f16, pre-scaled 1/C).
// Merged epilogue: per (d, row) writes 16 consecutive x = full 64B lines.
__global__ __launch_bounds__(256, 3)
void corr3(const _Float16* __restrict__ f1t, const _Float16* __restrict__ f2t,
           float* __restrict__ out) {
  __shared__ _Float16 G[2][32 * GPITCH];  // 50,688 B -> 3 wg/CU

  // bijective XCD swizzle: 3072 wgs = 8 XCDs x 384 contiguous
  int bid = (int)blockIdx.x;
  bid = (bid & 7) * 384 + (bid >> 3);
  const int tx = bid % NTX;
  int tmp = bid / NTX;
  const int ty = tmp % NTY;
  tmp /= NTY;
  const int qa = tmp & 1;
  tmp >>= 1;
  const int chunk = tmp & 1;
  const int b = tmp >> 1;
  const int y0 = ty * TY, x0 = tx * TX;
  const int i0 = chunk ? 11 : 0;        // window row offset
  const int nrows = chunk ? 13 : 14;
  const int NNc = nrows * NJ;           // 364 / 392
  const int ntiles = (NNc + 15) / 16;   // 23 / 25

  const int t = threadIdx.x;
  const int lane = t & 63;
  const int wave = t >> 6;
  const int l15 = lane & 15;
  const int lk = lane >> 4;

  const _Float16* f1b = f1t + (size_t)b * HW * Cn;
  const _Float16* f2b = f2t + (size_t)b * PHW * Cn;
  const float invc = 1.0f / 256.0f;

  for (int qb = 0; qb < 2; ++qb) {
    // A fragments for both m-tiles of this parity class (64 VGPR)
    half8 afrag[2][8];
#pragma unroll
    for (int mt = 0; mt < 2; ++mt) {
      const int m = mt * 16 + l15;
      const int ay = y0 + qa + 2 * (m >> 3);
      const int ax = x0 + qb + 2 * (m & 7);
      const _Float16* ap = f1b + (size_t)(ay * Wn + ax) * Cn + lk * 8;
#pragma unroll
      for (int ks = 0; ks < 8; ++ks)
        afrag[mt][ks] = *(const half8*)(ap + ks * 32);
    }

    for (int nt = wave; nt < ntiles; nt += 4) {
      const int n = nt * 16 + l15;
      const bool nvalid = n < NNc;
      const int nc = nvalid ? n : 0;
      const int i = nc / NJ + i0;
      const int j = nc % NJ;
      const int py = y0 + qa + 2 * i;   // padded coords
      const int px = x0 + qb + 2 * j;
      const _Float16* bp = f2b + (size_t)(py * PW + px) * Cn + lk * 8;
      half8 bfrag[8];
#pragma unroll
      for (int ks = 0; ks < 8; ++ks)
        bfrag[ks] = *(const half8*)(bp + ks * 32);

      floatx4 acc0 = {0.f, 0.f, 0.f, 0.f};
      floatx4 acc1 = {0.f, 0.f, 0.f, 0.f};
#pragma unroll
      for (int ks = 0; ks < 8; ++ks) {
        acc0 = __builtin_amdgcn_mfma_f32_16x16x32_f16(afrag[0][ks], bfrag[ks], acc0, 0, 0, 0);
        acc1 = __builtin_amdgcn_mfma_f32_16x16x32_f16(afrag[1][ks], bfrag[ks], acc1, 0, 0, 0);
      }
      if (nvalid) {
#pragma unroll
        for (int r = 0; r < 4; ++r) {
          G[qb][(4 * lk + r) * GPITCH + n]        = (_Float16)(acc0[r] * invc);
          G[qb][(16 + 4 * lk + r) * GPITCH + n]   = (_Float16)(acc1[r] * invc);
        }
      }
    }
  }
  __syncthreads();

  // merged epilogue for this chunk's dy range:
  // chunk 0: dy in [0,10] (231 ch); chunk 1: dy in [11,20] (210 ch)
  // thread t -> (d-sub = t>>4, alpha = (t>>2)&3, x-quad = t&3); each lane
  // writes float4 covering x = x0+xq*4 .. +3 -> 4 lanes cover a 64B line.
  {
    const int dyLo = chunk ? 11 : 0;
    const int ndch = chunk ? 210 : 231;
    const int niter = (ndch + 15) / 16;   // 14 / 15
    const int dsub = t >> 4;
    const int alpha = (t >> 2) & 3;
    const int xq = t & 3;
    const int yy = y0 + qa + 2 * alpha;
    float* ob = out + (size_t)b * ND * HW + yy * Wn + x0 + xq * 4;
    const int m0 = alpha * 8 + xq * 2;
    for (int q = 0; q < niter; ++q) {
      const int dch = q * 16 + dsub;
      if (dch < ndch) {
        const unsigned dyl = (unsigned)dch / 21u;
        const int dx = dch - (int)dyl * 21;
        const int dy = dyLo + (int)dyl;
        const int col = (alpha + dy - i0) * NJ + xq * 2 + dx;
        floatx4 v;
        v[0] = (float)G[0][m0 * GPITCH + col];            // x even, beta=xq*2
        v[1] = (float)G[1][m0 * GPITCH + col];            // x odd
        v[2] = (float)G[0][(m0 + 1) * GPITCH + col + 1];  // beta=xq*2+1
        v[3] = (float)G[1][(m0 + 1) * GPITCH + col + 1];
        __builtin_nontemporal_store(v, (floatx4*)(ob + (size_t)(dy * Dn + dx) * HW));
      }
    }
  }
}

// ---------------- fallback (round-1 kernel) if ws too small ---------------
constexpr int FTY = 8, FTX = 8;
constexpr int FNTY = Hn / FTY, FNTX = Wn / FTX;
constexpr int FNJ = 24, FNTILES = 36, FGP = 580;

__global__ __launch_bounds__(256, 4)
void corr_fallback(const float* __restrict__ f1, const float* __restrict__ f2,
                   float* __restrict__ out) {
  __shared__ float G[16 * FGP];
  const int bid = blockIdx.x;
  const int cls = bid & 3;
  const int t2 = bid >> 2;
  const int tx = t2 % FNTX;
  const int t3 = t2 / FNTX;
  const int ty = t3 % FNTY;
  const int b = t3 / FNTY;
  const int qa = cls >> 1, qb = cls & 1;
  const int y0 = ty * FTY, x0 = tx * FTX;
  const int lane = threadIdx.x & 63;
  const int wave = threadIdx.x >> 6;
  const int l15 = lane & 15;
  const int lk = lane >> 4;
  const float* f1b = f1 + b * (Cn * HW);
  const float* f2b = f2 + b * (Cn * HW);
  const int ay = y0 + qa + 2 * (l15 >> 2);
  const int ax = x0 + qb + 2 * (l15 & 3);
  const float* f1p = f1b + ay * Wn + ax;
  half8 afrag[8];
#pragma unroll
  for (int ks = 0; ks < 8; ++ks)
#pragma unroll
    for (int tt = 0; tt < 8; ++tt)
      afrag[ks][tt] = (_Float16)f1p[(ks * 32 + lk * 8 + tt) * HW];
  const int nt0 = wave * (FNTILES / 4);
  for (int nt = nt0; nt < nt0 + FNTILES / 4; ++nt) {
    const unsigned n = nt * 16 + l15;
    const int i = n / (unsigned)FNJ;
    const int j = n % (unsigned)FNJ;
    const int y2 = y0 - 20 + qa + 2 * i;
    const int x2 = x0 - 20 + qb + 2 * j;
    const bool inb = (y2 >= 0) & (y2 < Hn) & (x2 >= 0) & (x2 < Wn);
    const float* f2p = f2b + (inb ? (y2 * Wn + x2) : 0);
    floatx4 acc = {0.f, 0.f, 0.f, 0.f};
#pragma unroll
    for (int ks = 0; ks < 8; ++ks) {
      half8 bfrag;
#pragma unroll
      for (int tt = 0; tt < 8; ++tt) {
        const float v = f2p[(ks * 32 + lk * 8 + tt) * HW];
        bfrag[tt] = (_Float16)(inb ? v : 0.0f);
      }
      acc = __builtin_amdgcn_mfma_f32_16x16x32_f16(afrag[ks], bfrag, acc, 0, 0, 0);
    }
#pragma unroll
    for (int r = 0; r < 4; ++r)
      G[(4 * lk + r) * FGP + n] = acc[r];
  }
  __syncthreads();
  float* outb = out + b * (ND * HW);
  const float invc = 1.0f / 256.0f;
  for (int o = threadIdx.x; o < ND * 16; o += 256) {
    const int d = o >> 4;
    const int m = o & 15;
    const int dy = (unsigned)d / 21u;
    const int dx = (unsigned)d % 21u;
    const int alpha = m >> 2, beta = m & 3;
    const float val = G[m * FGP + (alpha + dy) * FNJ + (beta + dx)] * invc;
    outb[d * HW + (y0 + qa + 2 * alpha) * Wn + (x0 + qb + 2 * beta)] = val;
  }
}

extern "C" void kernel_launch(void* const* d_in, const int* in_sizes, int n_in,
                              void* d_out, int out_size, void* d_ws, size_t ws_size,
                              hipStream_t stream) {
  const float* f1 = (const float*)d_in[0];
  const float* f2 = (const float*)d_in[1];
  float* out = (float*)d_out;
  if (ws_size >= WS_NEEDED) {
    _Float16* f1t = (_Float16*)d_ws;
    _Float16* f2t = (_Float16*)((char*)d_ws + F1T_BYTES);
    tconv_all<<<dim3(F1_BLKS + F2_BLKS), dim3(256), 0, stream>>>(f1, f2, f1t, f2t);
    corr3<<<dim3(Bn * 2 * NTY * NTX * 2), dim3(256), 0, stream>>>(f1t, f2t, out);
  } else {
    corr_fallback<<<dim3(Bn * FNTY * FNTX * 4), dim3(256), 0, stream>>>(f1, f2, out);
  }
}

// Round 5
// 276.119 us; speedup vs baseline: 1.4118x; 1.0333x over previous
//
#include <hip/hip_runtime.h>

typedef _Float16 half8 __attribute__((ext_vector_type(8)));
typedef float floatx4 __attribute__((ext_vector_type(4)));

constexpr int Bn = 16, Cn = 256, Hn = 64, Wn = 96;
constexpr int HW = Hn * Wn;          // 6144
constexpr int Dn = 21, ND = Dn * Dn; // 441
// padded f2 spatial dims (pad=20 each side)
constexpr int PH = Hn + 40;          // 104
constexpr int PW = Wn + 40;          // 136
constexpr int PHW = PH * PW;         // 14144
// pass-2 tile
constexpr int TY = 8, TX = 16;
constexpr int NTY = Hn / TY;         // 8
constexpr int NTX = Wn / TX;         // 6
constexpr int NJ = (TX + 40) / 2;    // 28 window cols per parity
constexpr int GPITCH = 396;          // f16 pitch (4-row delta -> disjoint bank octets)
// LDS: 2 parity classes x 32 rows x 396 f16 = 50688 B -> 3 wg/CU

constexpr size_t F1T_BYTES = (size_t)Bn * HW * Cn * 2;   // 50,331,648
constexpr size_t F2T_BYTES = (size_t)Bn * PHW * Cn * 2;  // 115,867,648
constexpr size_t WS_NEEDED = F1T_BYTES + F2T_BYTES;

constexpr int F1_BLKS = Bn * (HW / 64);    // 1536
constexpr int F2_BLKS = Bn * (PHW / 64);   // 3536

// ---------------- pass 1 (merged): f32 BCHW -> f16 pixel-major ------------
__global__ __launch_bounds__(256)
void tconv_all(const float* __restrict__ f1, const float* __restrict__ f2,
               _Float16* __restrict__ f1t, _Float16* __restrict__ f2t) {
  int blk = blockIdx.x;
  const int t = threadIdx.x;
  const int pxl = t >> 2;            // 0..63
  const int g = t & 3;
  if (blk < F1_BLKS) {
    const int b = blk / (HW / 64);
    const int px = (blk % (HW / 64)) * 64 + pxl;
    const float* src = f1 + (size_t)b * Cn * HW + px;
    _Float16* dst = f1t + ((size_t)b * HW + px) * Cn;
#pragma unroll
    for (int it = 0; it < 8; ++it) {
      const int c0 = (g + it * 4) * 8;
      half8 v;
#pragma unroll
      for (int k = 0; k < 8; ++k)
        v[k] = (_Float16)src[(size_t)(c0 + k) * HW];
      *(half8*)(dst + c0) = v;
    }
  } else {
    blk -= F1_BLKS;
    const int b = blk / (PHW / 64);
    const int ppx = (blk % (PHW / 64)) * 64 + pxl;
    const int y = ppx / PW;
    const int x = ppx - y * PW;
    const int yy = y - 20, xx = x - 20;
    const bool valid = (yy >= 0) & (yy < Hn) & (xx >= 0) & (xx < Wn);
    const float* src = f2 + (size_t)b * Cn * HW + (valid ? (yy * Wn + xx) : 0);
    _Float16* dst = f2t + ((size_t)b * PHW + ppx) * Cn;
#pragma unroll
    for (int it = 0; it < 8; ++it) {
      const int c0 = (g + it * 4) * 8;
      half8 v;
#pragma unroll
      for (int k = 0; k < 8; ++k) {
        const float f = src[(size_t)(c0 + k) * HW];
        v[k] = (_Float16)(valid ? f : 0.0f);
      }
      *(half8*)(dst + c0) = v;
    }
  }
}

// ---------------- pass 2: correlation via MFMA ----------------------------
// One wg = (b, qa, 8x16 tile, window-row chunk), BOTH x-parity classes.
// A register-resident, B double-buffered (next tile's loads in flight
// across current tile's MFMAs). Merged full-line epilogue.
__global__ __launch_bounds__(256, 3)
void corr3(const _Float16* __restrict__ f1t, const _Float16* __restrict__ f2t,
           float* __restrict__ out) {
  __shared__ _Float16 G[2][32 * GPITCH];  // 50,688 B -> 3 wg/CU

  // bijective XCD swizzle: 3072 wgs = 8 XCDs x 384 contiguous
  int bid = (int)blockIdx.x;
  bid = (bid & 7) * 384 + (bid >> 3);
  const int tx = bid % NTX;
  int tmp = bid / NTX;
  const int ty = tmp % NTY;
  tmp /= NTY;
  const int qa = tmp & 1;
  tmp >>= 1;
  const int chunk = tmp & 1;
  const int b = tmp >> 1;
  const int y0 = ty * TY, x0 = tx * TX;
  const int i0 = chunk ? 11 : 0;        // window row offset
  const int nrows = chunk ? 13 : 14;
  const int NNc = nrows * NJ;           // 364 / 392
  const int ntiles = (NNc + 15) / 16;   // 23 / 25

  const int t = threadIdx.x;
  const int lane = t & 63;
  const int wave = t >> 6;
  const int l15 = lane & 15;
  const int lk = lane >> 4;

  const _Float16* f1b = f1t + (size_t)b * HW * Cn;
  const _Float16* f2b = f2t + (size_t)b * PHW * Cn;
  const float invc = 1.0f / 256.0f;

  for (int qb = 0; qb < 2; ++qb) {
    // ---- A fragments for both m-tiles, loaded once and pinned in registers
    half8 afrag0[8], afrag1[8];
    {
      const int m0 = l15;
      const int m1 = 16 + l15;
      const _Float16* ap0 = f1b + (size_t)((y0 + qa + 2 * (m0 >> 3)) * Wn + x0 + qb + 2 * (m0 & 7)) * Cn + lk * 8;
      const _Float16* ap1 = f1b + (size_t)((y0 + qa + 2 * (m1 >> 3)) * Wn + x0 + qb + 2 * (m1 & 7)) * Cn + lk * 8;
#pragma unroll
      for (int ks = 0; ks < 8; ++ks) {
        afrag0[ks] = *(const half8*)(ap0 + ks * 32);
        afrag1[ks] = *(const half8*)(ap1 + ks * 32);
      }
    }
    // pin A in registers: a no-op use prevents the compiler from re-sinking
    // the loads into the nt loop (round-4 showed VGPR=68 => A reloaded/tile)
#pragma unroll
    for (int ks = 0; ks < 8; ++ks)
      asm volatile("" :: "v"(afrag0[ks]), "v"(afrag1[ks]));

    const _Float16* f2base = f2b + (size_t)((y0 + qa) * PW + (x0 + qb)) * Cn + lk * 8;

    // address of tile nt for this lane (clamped for edge-tile lanes)
    auto bptr = [&](int nt) -> const _Float16* {
      const int n = nt * 16 + l15;
      const int nc = (n < NNc) ? n : 0;
      const int i = nc / NJ + i0;
      const int j = nc % NJ;
      return f2base + (size_t)(2 * i * PW + 2 * j) * Cn;
    };
    auto loadB = [&](const _Float16* bp, half8* bf) {
#pragma unroll
      for (int ks = 0; ks < 8; ++ks)
        bf[ks] = *(const half8*)(bp + ks * 32);
    };
    auto compute = [&](int nt, half8* bf) {
      floatx4 acc0 = {0.f, 0.f, 0.f, 0.f};
      floatx4 acc1 = {0.f, 0.f, 0.f, 0.f};
#pragma unroll
      for (int ks = 0; ks < 8; ++ks) {
        acc0 = __builtin_amdgcn_mfma_f32_16x16x32_f16(afrag0[ks], bf[ks], acc0, 0, 0, 0);
        acc1 = __builtin_amdgcn_mfma_f32_16x16x32_f16(afrag1[ks], bf[ks], acc1, 0, 0, 0);
      }
      const int n = nt * 16 + l15;
      if (n < NNc) {
#pragma unroll
        for (int r = 0; r < 4; ++r) {
          G[qb][(4 * lk + r) * GPITCH + n]      = (_Float16)(acc0[r] * invc);
          G[qb][(16 + 4 * lk + r) * GPITCH + n] = (_Float16)(acc1[r] * invc);
        }
      }
    };

    // ---- software-pipelined nt loop, 2-deep, statically named buffers
    half8 bufA[8], bufB[8];
    int nt = wave;
    if (nt < ntiles) loadB(bptr(nt), bufA);
    while (nt < ntiles) {
      const int ntN1 = nt + 4;
      if (ntN1 < ntiles) loadB(bptr(ntN1), bufB);
      compute(nt, bufA);
      nt = ntN1;
      if (nt >= ntiles) break;
      const int ntN2 = nt + 4;
      if (ntN2 < ntiles) loadB(bptr(ntN2), bufA);
      compute(nt, bufB);
      nt = ntN2;
    }
  }
  __syncthreads();

  // merged epilogue for this chunk's dy range:
  // chunk 0: dy in [0,10] (231 ch); chunk 1: dy in [11,20] (210 ch)
  // thread t -> (d-sub = t>>4, alpha = (t>>2)&3, x-quad = t&3); each lane
  // writes float4 covering x = x0+xq*4 .. +3 -> 4 lanes cover a 64B line.
  {
    const int dyLo = chunk ? 11 : 0;
    const int ndch = chunk ? 210 : 231;
    const int niter = (ndch + 15) / 16;   // 14 / 15
    const int dsub = t >> 4;
    const int alpha = (t >> 2) & 3;
    const int xq = t & 3;
    const int yy = y0 + qa + 2 * alpha;
    float* ob = out + (size_t)b * ND * HW + yy * Wn + x0 + xq * 4;
    const int m0 = alpha * 8 + xq * 2;
    for (int q = 0; q < niter; ++q) {
      const int dch = q * 16 + dsub;
      if (dch < ndch) {
        const unsigned dyl = (unsigned)dch / 21u;
        const int dx = dch - (int)dyl * 21;
        const int dy = dyLo + (int)dyl;
        const int col = (alpha + dy - i0) * NJ + xq * 2 + dx;
        floatx4 v;
        v[0] = (float)G[0][m0 * GPITCH + col];            // x even, beta=xq*2
        v[1] = (float)G[1][m0 * GPITCH + col];            // x odd
        v[2] = (float)G[0][(m0 + 1) * GPITCH + col + 1];  // beta=xq*2+1
        v[3] = (float)G[1][(m0 + 1) * GPITCH + col + 1];
        __builtin_nontemporal_store(v, (floatx4*)(ob + (size_t)(dy * Dn + dx) * HW));
      }
    }
  }
}

// ---------------- fallback (round-1 kernel) if ws too small ---------------
constexpr int FTY = 8, FTX = 8;
constexpr int FNTY = Hn / FTY, FNTX = Wn / FTX;
constexpr int FNJ = 24, FNTILES = 36, FGP = 580;

__global__ __launch_bounds__(256, 4)
void corr_fallback(const float* __restrict__ f1, const float* __restrict__ f2,
                   float* __restrict__ out) {
  __shared__ float G[16 * FGP];
  const int bid = blockIdx.x;
  const int cls = bid & 3;
  const int t2 = bid >> 2;
  const int tx = t2 % FNTX;
  const int t3 = t2 / FNTX;
  const int ty = t3 % FNTY;
  const int b = t3 / FNTY;
  const int qa = cls >> 1, qb = cls & 1;
  const int y0 = ty * FTY, x0 = tx * FTX;
  const int lane = threadIdx.x & 63;
  const int wave = threadIdx.x >> 6;
  const int l15 = lane & 15;
  const int lk = lane >> 4;
  const float* f1b = f1 + b * (Cn * HW);
  const float* f2b = f2 + b * (Cn * HW);
  const int ay = y0 + qa + 2 * (l15 >> 2);
  const int ax = x0 + qb + 2 * (l15 & 3);
  const float* f1p = f1b + ay * Wn + ax;
  half8 afrag[8];
#pragma unroll
  for (int ks = 0; ks < 8; ++ks)
#pragma unroll
    for (int tt = 0; tt < 8; ++tt)
      afrag[ks][tt] = (_Float16)f1p[(ks * 32 + lk * 8 + tt) * HW];
  const int nt0 = wave * (FNTILES / 4);
  for (int nt = nt0; nt < nt0 + FNTILES / 4; ++nt) {
    const unsigned n = nt * 16 + l15;
    const int i = n / (unsigned)FNJ;
    const int j = n % (unsigned)FNJ;
    const int y2 = y0 - 20 + qa + 2 * i;
    const int x2 = x0 - 20 + qb + 2 * j;
    const bool inb = (y2 >= 0) & (y2 < Hn) & (x2 >= 0) & (x2 < Wn);
    const float* f2p = f2b + (inb ? (y2 * Wn + x2) : 0);
    floatx4 acc = {0.f, 0.f, 0.f, 0.f};
#pragma unroll
    for (int ks = 0; ks < 8; ++ks) {
      half8 bfrag;
#pragma unroll
      for (int tt = 0; tt < 8; ++tt) {
        const float v = f2p[(ks * 32 + lk * 8 + tt) * HW];
        bfrag[tt] = (_Float16)(inb ? v : 0.0f);
      }
      acc = __builtin_amdgcn_mfma_f32_16x16x32_f16(afrag[ks], bfrag, acc, 0, 0, 0);
    }
#pragma unroll
    for (int r = 0; r < 4; ++r)
      G[(4 * lk + r) * FGP + n] = acc[r];
  }
  __syncthreads();
  float* outb = out + b * (ND * HW);
  const float invc = 1.0f / 256.0f;
  for (int o = threadIdx.x; o < ND * 16; o += 256) {
    const int d = o >> 4;
    const int m = o & 15;
    const int dy = (unsigned)d / 21u;
    const int dx = (unsigned)d % 21u;
    const int alpha = m >> 2, beta = m & 3;
    const float val = G[m * FGP + (alpha + dy) * FNJ + (beta + dx)] * invc;
    outb[d * HW + (y0 + qa + 2 * alpha) * Wn + (x0 + qb + 2 * beta)] = val;
  }
}

extern "C" void kernel_launch(void* const* d_in, const int* in_sizes, int n_in,
                              void* d_out, int out_size, void* d_ws, size_t ws_size,
                              hipStream_t stream) {
  const float* f1 = (const float*)d_in[0];
  const float* f2 = (const float*)d_in[1];
  float* out = (float*)d_out;
  if (ws_size >= WS_NEEDED) {
    _Float16* f1t = (_Float16*)d_ws;
    _Float16* f2t = (_Float16*)((char*)d_ws + F1T_BYTES);
    tconv_all<<<dim3(F1_BLKS + F2_BLKS), dim3(256), 0, stream>>>(f1, f2, f1t, f2t);
    corr3<<<dim3(Bn * 2 * NTY * NTX * 2), dim3(256), 0, stream>>>(f1t, f2t, out);
  } else {
    corr_fallback<<<dim3(Bn * FNTY * FNTX * 4), dim3(256), 0, stream>>>(f1, f2, out);
  }
}